// Round 6
// baseline (626.363 us; speedup 1.0000x reference)
//
#include <hip/hip_runtime.h>
#include <hip/hip_bf16.h>

// ParallelDense: y[b,m,u] = relu(sum_f x[b,m,f] * W[m,f,u] + bias[m,u])
// B=2048, M=64, F=512, U=512.
// R5 (4th resubmit after broker timeouts): X pre-staged to bf16 mask-major
// Xp[m][b][f] (x_prep). Main loop A-path now identical to B-path (bf16,
// 64B rows, XOR-swizzled chunks): 4 gld16/tile (was 6), 8 ds_read_b128/iter
// (was 12 + 16 cvt). 3 LDS buffers (48KB, 3 blocks/CU) with 2-tile-deep
// prefetch: s_waitcnt vmcnt(8) keeps two tiles in flight -> each tile
// covered by TWO compute phases.
// Fallbacks: ws >= 33.5MB -> R4 f32-A kernel; else R1 kernel.

typedef __attribute__((ext_vector_type(8))) short bf16x8;
typedef __attribute__((ext_vector_type(4))) float f32x4;

#define LDS_S 40   // (fallback kernel only)

__device__ __forceinline__ unsigned pk_bf16(float a, float b) {
    float2 t; t.x = a; t.y = b;
    __hip_bfloat162 h = __float22bfloat162_rn(t);   // v_cvt_pk_bf16_f32 (RNE)
    union { __hip_bfloat162 h; unsigned u; } cv;
    cv.h = h;
    return cv.u;
}

__device__ __forceinline__ void gld16(const void* g, void* l) {
    __builtin_amdgcn_global_load_lds(
        (const __attribute__((address_space(1))) void*)g,
        (__attribute__((address_space(3))) void*)l, 16, 0, 0);
}

// ---------------- prep 1: X[b][m][f] fp32 -> Xp[m][b][f] bf16 ----------------
// Block = one m x 8 b-rows. Reads 512B-contiguous per 32-lane group,
// writes 256B-contiguous bf16 segments. Grid (256, 64) x 256 threads.
__global__ void x_prep_kernel(const float* __restrict__ X, short* __restrict__ Xp) {
    const int m  = blockIdx.y;
    const int b0 = blockIdx.x * 8;
    const int t  = threadIdx.x;        // 0..255
    const int r  = t >> 5;             // 0..7 row within group
    const int c  = t & 31;             // float4 slot
    const float* src = X + ((size_t)(b0 + r) * 64 + m) * 512;
    short* dst = Xp + (size_t)m * 1048576 + (size_t)(b0 + r) * 512;
    #pragma unroll
    for (int i = 0; i < 4; ++i) {
        float4 v = *(const float4*)(src + (size_t)(c + i * 32) * 4);
        uint2 w;
        w.x = pk_bf16(v.x, v.y);
        w.y = pk_bf16(v.z, v.w);
        *(uint2*)(dst + (size_t)(c + i * 32) * 4) = w;
    }
}

// ---------------- prep 2: W[m][f][u] fp32 -> Wt[m][u][f] bf16 ----------------
__global__ void wt_prep_kernel(const float* __restrict__ W, short* __restrict__ Wt) {
    __shared__ short t[64][80];     // stride 160B (16B-aligned rows), 10KB
    const int m   = blockIdx.z;
    const int f0  = blockIdx.y * 64;
    const int u0  = blockIdx.x * 64;
    const int tid = threadIdx.x;    // 0..255
    const int fl  = tid >> 4;       // 0..15
    const int us  = tid & 15;       // 16B slot (4 u-values)
    #pragma unroll
    for (int i = 0; i < 4; ++i) {
        const int f = fl + 16 * i;
        float4 v = *(const float4*)(W + ((size_t)m * 512 + f0 + f) * 512 + u0 + us * 4);
        t[us * 4 + 0][f] = (short)(pk_bf16(v.x, v.x) & 0xffff);
        t[us * 4 + 1][f] = (short)(pk_bf16(v.y, v.y) & 0xffff);
        t[us * 4 + 2][f] = (short)(pk_bf16(v.z, v.z) & 0xffff);
        t[us * 4 + 3][f] = (short)(pk_bf16(v.w, v.w) & 0xffff);
    }
    __syncthreads();
    const int ur = tid >> 3;        // 0..31
    const int fs = tid & 7;         // 16B slot within f-row
    #pragma unroll
    for (int i = 0; i < 2; ++i) {
        const int u = ur + 32 * i;
        *(uint4*)(Wt + ((size_t)m * 512 + u0 + u) * 512 + f0 + fs * 8) =
            *(const uint4*)&t[u][fs * 8];
    }
}

// ---------------- main GEMM (R5: bf16 A, 3-buffer, depth-2 prefetch) ----------
// LDS layout (both A and B, unpadded for global_load_lds, XOR-swizzled):
//   row r (128 rows) = 32 bf16 = 4 chunks of 16B; chunk c stored at
//   position c ^ ((r>>1)&3) -> 2-way bank access on ds_read_b128 (free).
// Pipeline per iter kt (fully unrolled, 16 iters):
//   s_barrier                 (all waves done reading buf[(kt-1)%3])
//   issue 4 DMAs tile kt+2 -> buf[(kt+2)%3]
//   s_waitcnt vmcnt(8)        (tile kt landed; kt+1,kt+2 stay in flight)
//   s_barrier                 (everyone's tile kt landed)
//   8 ds_read_b128 + 16 MFMA on buf[kt%3]
__global__ __launch_bounds__(256, 3) void pdense_main2(const short* __restrict__ Xp,
                                                       const short* __restrict__ Wt,
                                                       const float* __restrict__ bias,
                                                       float* __restrict__ Out) {
    __shared__ short lds[3][2][128 * 32];   // [buf][A/B][...]  48 KB total

    const int tid  = threadIdx.x;
    const int lane = tid & 63;
    const int wave = tid >> 6;
    const int q    = lane >> 4;           // quad -> k-chunk q
    const int ln   = lane & 15;
    const int wr   = (wave >> 1) * 64;
    const int wc   = (wave & 1) * 64;

    // XCD swizzle: id&7 = XCD; each XCD owns 8 masks; within an XCD,
    // consecutive slots = 4 ut-blocks sharing the same x rows.
    const int id   = blockIdx.x;
    const int xcd  = id & 7;
    const int slot = id >> 3;
    const int m    = xcd * 8 + (slot >> 6);
    const int rem  = slot & 63;
    const int bt   = rem >> 2;
    const int ut   = rem & 3;
    const int row0 = bt * 128;
    const int col0 = ut * 128;

    // ---- DMA source addresses (identical scheme for A and B) ----
    // instr j covers rows wave*32 + j*16 .. +15 (16 rows x 32 bf16 = 1KB).
    // lane l -> row l>>2, stored chunk pos l&3 -> global chunk c = (l&3)^((l>>3)&3).
    const int srow = wave * 32 + (lane >> 2);
    const int sc   = (lane & 3) ^ ((lane >> 3) & 3);
    const short* agp = Xp + (size_t)m * 1048576 + (size_t)(row0 + srow) * 512 + sc * 8;
    const short* bgp = Wt + (size_t)m * 262144 + (size_t)(col0 + srow) * 512 + sc * 8;

    f32x4 acc[4][4];
    #pragma unroll
    for (int i = 0; i < 4; ++i)
        #pragma unroll
        for (int j = 0; j < 4; ++j)
            acc[i][j] = (f32x4)0.0f;

    // prologue: DMA tiles 0,1 into buffers 0,1
    #pragma unroll
    for (int t = 0; t < 2; ++t) {
        #pragma unroll
        for (int j = 0; j < 2; ++j) {
            gld16(agp + t * 32 + (size_t)j * 16 * 512, &lds[t][0][(wave * 32 + j * 16) * 32]);
            gld16(bgp + t * 32 + (size_t)j * 16 * 512, &lds[t][1][(wave * 32 + j * 16) * 32]);
        }
    }

    const int s1 = (ln >> 1) & 3;

    #pragma unroll
    for (int kt = 0; kt < 16; ++kt) {
        const int cur = kt % 3;

        // BARRIER A: all waves finished reading buf[(kt-1)%3] (its frags were
        // consumed by iter kt-1's MFMAs before this point in program order)
        __builtin_amdgcn_sched_barrier(0);
        __builtin_amdgcn_s_barrier();
        __builtin_amdgcn_sched_barrier(0);

        // issue tile kt+2 into buf[(kt+2)%3]
        if (kt + 2 < 16) {
            const int nb = (kt + 2) % 3;
            const int ko = (kt + 2) * 32;
            #pragma unroll
            for (int j = 0; j < 2; ++j) {
                gld16(agp + ko + (size_t)j * 16 * 512, &lds[nb][0][(wave * 32 + j * 16) * 32]);
                gld16(bgp + ko + (size_t)j * 16 * 512, &lds[nb][1][(wave * 32 + j * 16) * 32]);
            }
        }
        __builtin_amdgcn_sched_barrier(0);
        if (kt < 14) {
            asm volatile("s_waitcnt vmcnt(8)" ::: "memory");
        } else if (kt == 14) {
            asm volatile("s_waitcnt vmcnt(4)" ::: "memory");
        } else {
            asm volatile("s_waitcnt vmcnt(0)" ::: "memory");
        }
        __builtin_amdgcn_sched_barrier(0);

        // BARRIER B: everyone's tile kt has landed in buf[cur]
        __builtin_amdgcn_s_barrier();
        __builtin_amdgcn_sched_barrier(0);

        // ---- fragments (swizzled ds_read_b128) + MFMA on buf[cur] ----
        bf16x8 aF[4], bF[4];
        #pragma unroll
        for (int i = 0; i < 4; ++i) {
            const int r = wr + i * 16 + ln;
            aF[i] = *(const bf16x8*)&lds[cur][0][r * 32 + ((q ^ s1) << 3)];
        }
        #pragma unroll
        for (int j = 0; j < 4; ++j) {
            const int r = wc + j * 16 + ln;
            bF[j] = *(const bf16x8*)&lds[cur][1][r * 32 + ((q ^ s1) << 3)];
        }
        #pragma unroll
        for (int i = 0; i < 4; ++i)
            #pragma unroll
            for (int j = 0; j < 4; ++j)
                acc[i][j] = __builtin_amdgcn_mfma_f32_16x16x32_bf16(aF[i], bF[j], acc[i][j], 0, 0, 0);
    }

    // epilogue: bias + relu + store. D map: col = lane&15, row = quad*4 + reg
    #pragma unroll
    for (int j = 0; j < 4; ++j) {
        const int c = col0 + wc + j * 16 + ln;
        const float bv = bias[m * 512 + c];
        #pragma unroll
        for (int i = 0; i < 4; ++i) {
            const int r = row0 + wr + i * 16 + q * 4;
            float* op = Out + (size_t)r * 32768 + m * 512 + c;
            f32x4 v = acc[i][j];
            #pragma unroll
            for (int t = 0; t < 4; ++t) {
                float val = v[t] + bv;
                op[(size_t)t * 32768] = val > 0.0f ? val : 0.0f;
            }
        }
    }
}

// ---------------- R4 main (fp32 A), used if ws fits Wt only ----------------
__global__ __launch_bounds__(256, 3) void pdense_main(const float* __restrict__ X,
                                                      const short* __restrict__ Wt,
                                                      const float* __restrict__ bias,
                                                      float* __restrict__ Out) {
    __shared__ float ldsA[2][128 * 32];   // 16 KB each
    __shared__ short ldsB[2][128 * 32];   //  8 KB each   (total 48 KB)

    const int tid  = threadIdx.x;
    const int lane = tid & 63;
    const int wave = tid >> 6;
    const int q    = lane >> 4;
    const int ln   = lane & 15;
    const int wr   = (wave >> 1) * 64;
    const int wc   = (wave & 1) * 64;

    const int id   = blockIdx.x;
    const int xcd  = id & 7;
    const int slot = id >> 3;
    const int m    = xcd * 8 + (slot >> 6);
    const int rem  = slot & 63;
    const int bt   = rem >> 2;
    const int ut   = rem & 3;
    const int row0 = bt * 128;
    const int col0 = ut * 128;

    const int arow = wave * 32 + (lane >> 3);
    const int ac   = (lane & 7) ^ (lane >> 3);
    const float* agp = X + (size_t)(row0 + arow) * 32768 + m * 512 + ac * 4;
    const int brow = wave * 32 + (lane >> 2);
    const int bc   = (lane & 3) ^ ((lane >> 3) & 3);
    const short* bgp = Wt + (size_t)m * 262144 + (size_t)(col0 + brow) * 512 + bc * 8;

    f32x4 acc[4][4];
    #pragma unroll
    for (int i = 0; i < 4; ++i)
        #pragma unroll
        for (int j = 0; j < 4; ++j)
            acc[i][j] = (f32x4)0.0f;

    #pragma unroll
    for (int i = 0; i < 4; ++i)
        gld16(agp + (size_t)i * 8 * 32768, &ldsA[0][(wave * 32 + i * 8) * 32]);
    #pragma unroll
    for (int j = 0; j < 2; ++j)
        gld16(bgp + (size_t)j * 16 * 512, &ldsB[0][(wave * 32 + j * 16) * 32]);

    const int s1 = (ln >> 1) & 3;
    const int s0 = ln & 1;

    for (int kt = 0; kt < 16; ++kt) {
        const int p = kt & 1;

        __builtin_amdgcn_sched_barrier(0);
        __builtin_amdgcn_s_barrier();
        __builtin_amdgcn_sched_barrier(0);

        if (kt + 1 < 16) {
            const int ko = (kt + 1) * 32;
            #pragma unroll
            for (int i = 0; i < 4; ++i)
                gld16(agp + ko + (size_t)i * 8 * 32768, &ldsA[p ^ 1][(wave * 32 + i * 8) * 32]);
            #pragma unroll
            for (int j = 0; j < 2; ++j)
                gld16(bgp + ko + (size_t)j * 16 * 512, &ldsB[p ^ 1][(wave * 32 + j * 16) * 32]);
            __builtin_amdgcn_sched_barrier(0);
            asm volatile("s_waitcnt vmcnt(6)" ::: "memory");
        } else {
            asm volatile("s_waitcnt vmcnt(0)" ::: "memory");
        }
        __builtin_amdgcn_sched_barrier(0);

        __builtin_amdgcn_s_barrier();
        __builtin_amdgcn_sched_barrier(0);

        bf16x8 aF[4], bF[4];
        #pragma unroll
        for (int i = 0; i < 4; ++i) {
            const int r = wr + i * 16 + ln;
            const float* base = &ldsA[p][r * 32 + ((q ^ s1) << 3)];
            float4 ca = *(const float4*)(base + (s0 << 2));
            float4 cb = *(const float4*)(base + ((1 - s0) << 2));
            union { bf16x8 v; uint4 u; } fr;
            fr.u.x = pk_bf16(ca.x, ca.y);
            fr.u.y = pk_bf16(ca.z, ca.w);
            fr.u.z = pk_bf16(cb.x, cb.y);
            fr.u.w = pk_bf16(cb.z, cb.w);
            aF[i] = fr.v;
        }
        #pragma unroll
        for (int j = 0; j < 4; ++j) {
            const int r = wc + j * 16 + ln;
            bF[j] = *(const bf16x8*)&ldsB[p][r * 32 + ((q ^ s1) << 3)];
        }
        #pragma unroll
        for (int i = 0; i < 4; ++i)
            #pragma unroll
            for (int j = 0; j < 4; ++j)
                acc[i][j] = __builtin_amdgcn_mfma_f32_16x16x32_bf16(aF[i], bF[j], acc[i][j], 0, 0, 0);
    }

    #pragma unroll
    for (int j = 0; j < 4; ++j) {
        const int c = col0 + wc + j * 16 + ln;
        const float bv = bias[m * 512 + c];
        #pragma unroll
        for (int i = 0; i < 4; ++i) {
            const int r = row0 + wr + i * 16 + q * 4;
            float* op = Out + (size_t)r * 32768 + m * 512 + c;
            f32x4 v = acc[i][j];
            #pragma unroll
            for (int t = 0; t < 4; ++t) {
                float val = v[t] + bv;
                op[(size_t)t * 32768] = val > 0.0f ? val : 0.0f;
            }
        }
    }
}

// ---------------- fallback (R1 kernel, used if ws too small) ----------------
__global__ void pdense_fallback(const float* __restrict__ X,
                                const float* __restrict__ Wp,
                                const float* __restrict__ bias,
                                float* __restrict__ Out) {
    __shared__ short ldsA[128 * LDS_S];
    __shared__ short ldsB[128 * LDS_S];

    const int tid  = threadIdx.x;
    const int lane = tid & 63;
    const int wave = tid >> 6;
    const int q    = lane >> 4;
    const int ln   = lane & 15;
    const int wr   = (wave >> 1) * 64;
    const int wc   = (wave & 1) * 64;

    const int m    = blockIdx.y;
    const int bt   = blockIdx.x & 15;
    const int ut   = blockIdx.x >> 4;
    const int row0 = bt * 128;
    const int col0 = ut * 128;

    const int ar0 = tid >> 2;
    const int ak0 = (tid & 3) * 8;
    const int ar1 = ar0 + 64;
    const float* aP0 = X + (size_t)(row0 + ar0) * 32768 + m * 512 + ak0;
    const float* aP1 = X + (size_t)(row0 + ar1) * 32768 + m * 512 + ak0;

    const int k0 = (tid & 7) * 4;
    const int u0 = (tid >> 3) * 4;
    const float* bP = Wp + (size_t)m * 262144 + (size_t)k0 * 512 + col0 + u0;

    f32x4 acc[4][4];
    #pragma unroll
    for (int i = 0; i < 4; ++i)
        #pragma unroll
        for (int j = 0; j < 4; ++j)
            acc[i][j] = (f32x4)0.0f;

    float4 a_pre[2][2];
    float4 b_pre[4];

    a_pre[0][0] = ((const float4*)aP0)[0];
    a_pre[0][1] = ((const float4*)aP0)[1];
    a_pre[1][0] = ((const float4*)aP1)[0];
    a_pre[1][1] = ((const float4*)aP1)[1];
    #pragma unroll
    for (int i = 0; i < 4; ++i)
        b_pre[i] = *(const float4*)(bP + (size_t)i * 512);

    for (int kt = 0; kt < 16; ++kt) {
        {
            uint4 w0, w1;
            w0.x = pk_bf16(a_pre[0][0].x, a_pre[0][0].y);
            w0.y = pk_bf16(a_pre[0][0].z, a_pre[0][0].w);
            w0.z = pk_bf16(a_pre[0][1].x, a_pre[0][1].y);
            w0.w = pk_bf16(a_pre[0][1].z, a_pre[0][1].w);
            *(uint4*)&ldsA[ar0 * LDS_S + ak0] = w0;
            w1.x = pk_bf16(a_pre[1][0].x, a_pre[1][0].y);
            w1.y = pk_bf16(a_pre[1][0].z, a_pre[1][0].w);
            w1.z = pk_bf16(a_pre[1][1].x, a_pre[1][1].y);
            w1.w = pk_bf16(a_pre[1][1].z, a_pre[1][1].w);
            *(uint4*)&ldsA[ar1 * LDS_S + ak0] = w1;
            #pragma unroll
            for (int j = 0; j < 4; ++j) {
                float c0 = ((const float*)&b_pre[0])[j];
                float c1 = ((const float*)&b_pre[1])[j];
                float c2 = ((const float*)&b_pre[2])[j];
                float c3 = ((const float*)&b_pre[3])[j];
                uint2 wv;
                wv.x = pk_bf16(c0, c1);
                wv.y = pk_bf16(c2, c3);
                *(uint2*)&ldsB[(u0 + j) * LDS_S + k0] = wv;
            }
        }
        __syncthreads();

        if (kt + 1 < 16) {
            const int ko = (kt + 1) * 32;
            a_pre[0][0] = ((const float4*)(aP0 + ko))[0];
            a_pre[0][1] = ((const float4*)(aP0 + ko))[1];
            a_pre[1][0] = ((const float4*)(aP1 + ko))[0];
            a_pre[1][1] = ((const float4*)(aP1 + ko))[1];
            #pragma unroll
            for (int i = 0; i < 4; ++i)
                b_pre[i] = *(const float4*)(bP + (size_t)(ko + i) * 512);
        }

        bf16x8 aF[4], bF[4];
        #pragma unroll
        for (int i = 0; i < 4; ++i)
            aF[i] = *(const bf16x8*)&ldsA[(wr + i * 16 + ln) * LDS_S + q * 8];
        #pragma unroll
        for (int j = 0; j < 4; ++j)
            bF[j] = *(const bf16x8*)&ldsB[(wc + j * 16 + ln) * LDS_S + q * 8];
        #pragma unroll
        for (int i = 0; i < 4; ++i)
            #pragma unroll
            for (int j = 0; j < 4; ++j)
                acc[i][j] = __builtin_amdgcn_mfma_f32_16x16x32_bf16(aF[i], bF[j], acc[i][j], 0, 0, 0);

        __syncthreads();
    }

    #pragma unroll
    for (int j = 0; j < 4; ++j) {
        const int c = col0 + wc + j * 16 + ln;
        const float bv = bias[m * 512 + c];
        #pragma unroll
        for (int i = 0; i < 4; ++i) {
            const int r = row0 + wr + i * 16 + q * 4;
            float* op = Out + (size_t)r * 32768 + m * 512 + c;
            f32x4 v = acc[i][j];
            #pragma unroll
            for (int t = 0; t < 4; ++t) {
                float val = v[t] + bv;
                op[(size_t)t * 32768] = val > 0.0f ? val : 0.0f;
            }
        }
    }
}

extern "C" void kernel_launch(void* const* d_in, const int* in_sizes, int n_in,
                              void* d_out, int out_size, void* d_ws, size_t ws_size,
                              hipStream_t stream) {
    const float* x    = (const float*)d_in[0];   // [2048, 64, 512]
    const float* W    = (const float*)d_in[1];   // [64, 512, 512]
    const float* bias = (const float*)d_in[2];   // [64, 512]
    float* out = (float*)d_out;                  // [2048, 64*512]

    const size_t wt_bytes = (size_t)64 * 512 * 512 * sizeof(short);    // 33.55 MB
    const size_t xp_bytes = (size_t)2048 * 64 * 512 * sizeof(short);   // 134.2 MB
    if (ws_size >= wt_bytes + xp_bytes) {
        short* Wt = (short*)d_ws;
        short* Xp = (short*)((char*)d_ws + wt_bytes);
        hipLaunchKernelGGL(x_prep_kernel, dim3(256, 64), dim3(256), 0, stream, x, Xp);
        hipLaunchKernelGGL(wt_prep_kernel, dim3(8, 8, 64), dim3(256), 0, stream, W, Wt);
        hipLaunchKernelGGL(pdense_main2, dim3(4096), dim3(256), 0, stream, Xp, Wt, bias, out);
    } else if (ws_size >= wt_bytes) {
        short* Wt = (short*)d_ws;
        hipLaunchKernelGGL(wt_prep_kernel, dim3(8, 8, 64), dim3(256), 0, stream, W, Wt);
        hipLaunchKernelGGL(pdense_main, dim3(4096), dim3(256), 0, stream, x, Wt, bias, out);
    } else {
        hipLaunchKernelGGL(pdense_fallback, dim3(64, 64), dim3(256), 0, stream, x, W, bias, out);
    }
}

// Round 8
// 581.616 us; speedup vs baseline: 1.0769x; 1.0769x over previous
//
#include <hip/hip_runtime.h>
#include <hip/hip_bf16.h>

// ParallelDense: y[b,m,u] = relu(sum_f x[b,m,f] * W[m,f,u] + bias[m,u])
// B=2048, M=64, F=512, U=512.
// R7 (resubmit after broker timeout): FUSED reg-staged-A kernel. R5 showed
// depth-2 works (main < 162us) but the separate x_prep pass (~105us) made
// total WORSE (626 vs R4's 575). R7 keeps R5's 3-buffer / depth-2-B pipeline
// and proven read path, but converts X fp32->bf16 inside the main loop:
// global_load_dwordx4 -> regs (2-set ping-pong, issued 1 iter ahead) ->
// v_cvt_pk -> swizzled ds_write_b64. A tiles stay bf16 (8KB), LDS 48KB ->
// 3 blocks/CU. No x_prep pass.
// vmcnt: per iter issue 4 A-reg loads then 2 B-gld16; single vmcnt(2) at
// loop top waits {B(kt), aReg(kt+2)}, leaves B(kt+1)+B(kt+2) in flight.

typedef __attribute__((ext_vector_type(8))) short bf16x8;
typedef __attribute__((ext_vector_type(4))) float f32x4;

#define LDS_S 40   // (fallback kernel only)

__device__ __forceinline__ unsigned pk_bf16(float a, float b) {
    float2 t; t.x = a; t.y = b;
    __hip_bfloat162 h = __float22bfloat162_rn(t);   // v_cvt_pk_bf16_f32 (RNE)
    union { __hip_bfloat162 h; unsigned u; } cv;
    cv.h = h;
    return cv.u;
}

__device__ __forceinline__ void gld16(const void* g, void* l) {
    __builtin_amdgcn_global_load_lds(
        (const __attribute__((address_space(1))) void*)g,
        (__attribute__((address_space(3))) void*)l, 16, 0, 0);
}

// ---------------- prep: W[m][f][u] fp32 -> Wt[m][u][f] bf16 ----------------
__global__ void wt_prep_kernel(const float* __restrict__ W, short* __restrict__ Wt) {
    __shared__ short t[64][80];     // stride 160B (16B-aligned rows), 10KB
    const int m   = blockIdx.z;
    const int f0  = blockIdx.y * 64;
    const int u0  = blockIdx.x * 64;
    const int tid = threadIdx.x;    // 0..255
    const int fl  = tid >> 4;       // 0..15
    const int us  = tid & 15;       // 16B slot (4 u-values)
    #pragma unroll
    for (int i = 0; i < 4; ++i) {
        const int f = fl + 16 * i;
        float4 v = *(const float4*)(W + ((size_t)m * 512 + f0 + f) * 512 + u0 + us * 4);
        t[us * 4 + 0][f] = (short)(pk_bf16(v.x, v.x) & 0xffff);
        t[us * 4 + 1][f] = (short)(pk_bf16(v.y, v.y) & 0xffff);
        t[us * 4 + 2][f] = (short)(pk_bf16(v.z, v.z) & 0xffff);
        t[us * 4 + 3][f] = (short)(pk_bf16(v.w, v.w) & 0xffff);
    }
    __syncthreads();
    const int ur = tid >> 3;        // 0..31
    const int fs = tid & 7;         // 16B slot within f-row
    #pragma unroll
    for (int i = 0; i < 2; ++i) {
        const int u = ur + 32 * i;
        *(uint4*)(Wt + ((size_t)m * 512 + u0 + u) * 512 + f0 + fs * 8) =
            *(const uint4*)&t[u][fs * 8];
    }
}

// ---------------- main GEMM (R7: fused, reg-staged A, 3-buffer) ----------
// LDS layout (both A and B bf16, XOR-swizzled):
//   row r (128 rows) = 32 bf16 = 4 chunks of 16B; content chunk c stored at
//   position c ^ ((r>>1)&3).  Read path identical to R5 (HW-validated).
// Per iter kt (fully unrolled, 16 iters):
//   BARRIER A               (all waves done reading buf[(kt+2)%3])
//   vmcnt(2)                (B(kt) landed + aReg(kt+2) arrived; B(kt+1) flies)
//   cvt+ds_write A(kt+2) -> buf[(kt+2)%3]      [from ping-pong reg set]
//   issue aReg(kt+3) (4x global_load_dwordx4)
//   issue B(kt+2) (2x gld16) -> buf[(kt+2)%3]
//   lgkmcnt(0); BARRIER B   (my A-writes visible; everyone's tile kt ready)
//   8 ds_read_b128 + 16 MFMA on buf[kt%3]
__global__ __launch_bounds__(256, 3) void pdense_main3(const float* __restrict__ X,
                                                       const short* __restrict__ Wt,
                                                       const float* __restrict__ bias,
                                                       float* __restrict__ Out) {
    __shared__ short lds[3][2][128 * 32];   // [buf][A/B]  48 KB total

    const int tid  = threadIdx.x;
    const int lane = tid & 63;
    const int wave = tid >> 6;
    const int q    = lane >> 4;           // quad -> k-chunk q
    const int ln   = lane & 15;
    const int wr   = (wave >> 1) * 64;
    const int wc   = (wave & 1) * 64;

    // XCD swizzle: id&7 = XCD; each XCD owns 8 masks; within an XCD,
    // consecutive slots = 4 ut-blocks sharing the same x rows (L2 reuse of X).
    const int id   = blockIdx.x;
    const int xcd  = id & 7;
    const int slot = id >> 3;
    const int m    = xcd * 8 + (slot >> 6);
    const int rem  = slot & 63;
    const int bt   = rem >> 2;
    const int ut   = rem & 3;
    const int row0 = bt * 128;
    const int col0 = ut * 128;

    // ---- A source (fp32 X, reg-staged): instr i covers rows wave*32+i*8..+7;
    //      lane l -> row (l>>3), fp32-16B-chunk c4 = l&7. Contiguous 1KB/instr.
    const int ar  = wave * 32 + (lane >> 3);
    const int ac4 = lane & 7;
    const float* agp = X + (size_t)(row0 + ar) * 32768 + m * 512 + ac4 * 4;
    // LDS write offsets (short index): content chunk c = c4>>1, half = c4&1,
    // pos = c ^ ((r>>1)&3); short_idx = r*32 + pos*8 + half*4.
    int awoff[4];
    #pragma unroll
    for (int i = 0; i < 4; ++i) {
        const int r   = ar + i * 8;
        const int pos = (ac4 >> 1) ^ ((r >> 1) & 3);
        awoff[i] = r * 32 + pos * 8 + (ac4 & 1) * 4;
    }

    // ---- B source (bf16 Wt via gld16): same as R5 (validated).
    const int srow = wave * 32 + (lane >> 2);
    const int sc   = (lane & 3) ^ ((lane >> 3) & 3);
    const short* bgp = Wt + (size_t)m * 262144 + (size_t)(col0 + srow) * 512 + sc * 8;

    f32x4 acc[4][4];
    #pragma unroll
    for (int i = 0; i < 4; ++i)
        #pragma unroll
        for (int j = 0; j < 4; ++j)
            acc[i][j] = (f32x4)0.0f;

    float4 aA[4], aB[4];   // ping-pong A staging (2 tiles in flight)

    auto aload = [&](int kt2, float4 (&d)[4]) {
        const float* p = agp + kt2 * 32;
        #pragma unroll
        for (int i = 0; i < 4; ++i)
            d[i] = *(const float4*)(p + (size_t)i * 8 * 32768);
    };
    auto astore = [&](int b, const float4 (&s)[4]) {
        #pragma unroll
        for (int i = 0; i < 4; ++i) {
            uint2 w;
            w.x = pk_bf16(s[i].x, s[i].y);
            w.y = pk_bf16(s[i].z, s[i].w);
            *(uint2*)&lds[b][0][awoff[i]] = w;
        }
    };
    auto bload = [&](int kt2, int b) {
        const short* p = bgp + kt2 * 32;
        gld16(p,            &lds[b][1][(wave * 32) * 32]);
        gld16(p + 16 * 512, &lds[b][1][(wave * 32 + 16) * 32]);
    };

    // ---- prologue: A(0),A(1) via regs -> buf0,buf1; B(0),B(1) via gld16.
    aload(0, aA);
    __builtin_amdgcn_sched_barrier(0);
    aload(1, aB);
    __builtin_amdgcn_sched_barrier(0);
    asm volatile("s_waitcnt vmcnt(4)" ::: "memory");   // a(0) ready
    __builtin_amdgcn_sched_barrier(0);
    astore(0, aA);
    __builtin_amdgcn_sched_barrier(0);
    aload(2, aA);
    __builtin_amdgcn_sched_barrier(0);
    asm volatile("s_waitcnt vmcnt(4)" ::: "memory");   // a(1) ready
    __builtin_amdgcn_sched_barrier(0);
    astore(1, aB);
    __builtin_amdgcn_sched_barrier(0);
    bload(0, 0);
    bload(1, 1);
    __builtin_amdgcn_sched_barrier(0);
    // queue now (oldest->newest): [a(2) x4, B(0) x2, B(1) x2]

    const int s1 = (ln >> 1) & 3;

    #pragma unroll
    for (int kt = 0; kt < 16; ++kt) {
        const int cur = kt % 3;
        const int nb  = (kt + 2) % 3;
        const bool evn = (kt & 1) == 0;   // compile-time under full unroll

        // BARRIER A: all waves finished reading buf[nb] (it was cur at kt-1)
        __builtin_amdgcn_sched_barrier(0);
        __builtin_amdgcn_s_barrier();
        __builtin_amdgcn_sched_barrier(0);

        // wait: B(kt) landed in buf[cur] AND aReg(kt+2) arrived.
        // queue: [B(kt) x2, a(kt+2) x4, B(kt+1) x2] -> vmcnt(2) leaves B(kt+1).
        if (kt < 15) {
            asm volatile("s_waitcnt vmcnt(2)" ::: "memory");
        } else {
            asm volatile("s_waitcnt vmcnt(0)" ::: "memory");
        }
        __builtin_amdgcn_sched_barrier(0);

        if (kt + 2 < 16) {
            if (evn) astore(nb, aA); else astore(nb, aB);   // A(kt+2) -> LDS
        }
        __builtin_amdgcn_sched_barrier(0);
        if (kt + 3 < 16) {
            if (evn) aload(kt + 3, aB); else aload(kt + 3, aA);
        }
        __builtin_amdgcn_sched_barrier(0);
        if (kt + 2 < 16) {
            bload(kt + 2, nb);
        }
        __builtin_amdgcn_sched_barrier(0);
        asm volatile("s_waitcnt lgkmcnt(0)" ::: "memory");  // my A ds_writes done
        __builtin_amdgcn_sched_barrier(0);

        // BARRIER B: everyone's tile kt complete in buf[cur]
        __builtin_amdgcn_s_barrier();
        __builtin_amdgcn_sched_barrier(0);

        // ---- fragments (swizzled ds_read_b128) + MFMA on buf[cur] ----
        bf16x8 aF[4], bF[4];
        #pragma unroll
        for (int i = 0; i < 4; ++i) {
            const int r = wr + i * 16 + ln;
            aF[i] = *(const bf16x8*)&lds[cur][0][r * 32 + ((q ^ s1) << 3)];
        }
        #pragma unroll
        for (int j = 0; j < 4; ++j) {
            const int r = wc + j * 16 + ln;
            bF[j] = *(const bf16x8*)&lds[cur][1][r * 32 + ((q ^ s1) << 3)];
        }
        #pragma unroll
        for (int i = 0; i < 4; ++i)
            #pragma unroll
            for (int j = 0; j < 4; ++j)
                acc[i][j] = __builtin_amdgcn_mfma_f32_16x16x32_bf16(aF[i], bF[j], acc[i][j], 0, 0, 0);
    }

    // epilogue: bias + relu + store. D map: col = lane&15, row = quad*4 + reg
    #pragma unroll
    for (int j = 0; j < 4; ++j) {
        const int c = col0 + wc + j * 16 + ln;
        const float bv = bias[m * 512 + c];
        #pragma unroll
        for (int i = 0; i < 4; ++i) {
            const int r = row0 + wr + i * 16 + q * 4;
            float* op = Out + (size_t)r * 32768 + m * 512 + c;
            f32x4 v = acc[i][j];
            #pragma unroll
            for (int t = 0; t < 4; ++t) {
                float val = v[t] + bv;
                op[(size_t)t * 32768] = val > 0.0f ? val : 0.0f;
            }
        }
    }
}

// ---------------- fallback (R1 kernel, used if ws too small) ----------------
__global__ void pdense_fallback(const float* __restrict__ X,
                                const float* __restrict__ Wp,
                                const float* __restrict__ bias,
                                float* __restrict__ Out) {
    __shared__ short ldsA[128 * LDS_S];
    __shared__ short ldsB[128 * LDS_S];

    const int tid  = threadIdx.x;
    const int lane = tid & 63;
    const int wave = tid >> 6;
    const int q    = lane >> 4;
    const int ln   = lane & 15;
    const int wr   = (wave >> 1) * 64;
    const int wc   = (wave & 1) * 64;

    const int m    = blockIdx.y;
    const int bt   = blockIdx.x & 15;
    const int ut   = blockIdx.x >> 4;
    const int row0 = bt * 128;
    const int col0 = ut * 128;

    const int ar0 = tid >> 2;
    const int ak0 = (tid & 3) * 8;
    const int ar1 = ar0 + 64;
    const float* aP0 = X + (size_t)(row0 + ar0) * 32768 + m * 512 + ak0;
    const float* aP1 = X + (size_t)(row0 + ar1) * 32768 + m * 512 + ak0;

    const int k0 = (tid & 7) * 4;
    const int u0 = (tid >> 3) * 4;
    const float* bP = Wp + (size_t)m * 262144 + (size_t)k0 * 512 + col0 + u0;

    f32x4 acc[4][4];
    #pragma unroll
    for (int i = 0; i < 4; ++i)
        #pragma unroll
        for (int j = 0; j < 4; ++j)
            acc[i][j] = (f32x4)0.0f;

    float4 a_pre[2][2];
    float4 b_pre[4];

    a_pre[0][0] = ((const float4*)aP0)[0];
    a_pre[0][1] = ((const float4*)aP0)[1];
    a_pre[1][0] = ((const float4*)aP1)[0];
    a_pre[1][1] = ((const float4*)aP1)[1];
    #pragma unroll
    for (int i = 0; i < 4; ++i)
        b_pre[i] = *(const float4*)(bP + (size_t)i * 512);

    for (int kt = 0; kt < 16; ++kt) {
        {
            uint4 w0, w1;
            w0.x = pk_bf16(a_pre[0][0].x, a_pre[0][0].y);
            w0.y = pk_bf16(a_pre[0][0].z, a_pre[0][0].w);
            w0.z = pk_bf16(a_pre[0][1].x, a_pre[0][1].y);
            w0.w = pk_bf16(a_pre[0][1].z, a_pre[0][1].w);
            *(uint4*)&ldsA[ar0 * LDS_S + ak0] = w0;
            w1.x = pk_bf16(a_pre[1][0].x, a_pre[1][0].y);
            w1.y = pk_bf16(a_pre[1][0].z, a_pre[1][0].w);
            w1.z = pk_bf16(a_pre[1][1].x, a_pre[1][1].y);
            w1.w = pk_bf16(a_pre[1][1].z, a_pre[1][1].w);
            *(uint4*)&ldsA[ar1 * LDS_S + ak0] = w1;
            #pragma unroll
            for (int j = 0; j < 4; ++j) {
                float c0 = ((const float*)&b_pre[0])[j];
                float c1 = ((const float*)&b_pre[1])[j];
                float c2 = ((const float*)&b_pre[2])[j];
                float c3 = ((const float*)&b_pre[3])[j];
                uint2 wv;
                wv.x = pk_bf16(c0, c1);
                wv.y = pk_bf16(c2, c3);
                *(uint2*)&ldsB[(u0 + j) * LDS_S + k0] = wv;
            }
        }
        __syncthreads();

        if (kt + 1 < 16) {
            const int ko = (kt + 1) * 32;
            a_pre[0][0] = ((const float4*)(aP0 + ko))[0];
            a_pre[0][1] = ((const float4*)(aP0 + ko))[1];
            a_pre[1][0] = ((const float4*)(aP1 + ko))[0];
            a_pre[1][1] = ((const float4*)(aP1 + ko))[1];
            #pragma unroll
            for (int i = 0; i < 4; ++i)
                b_pre[i] = *(const float4*)(bP + (size_t)(ko + i) * 512);
        }

        bf16x8 aF[4], bF[4];
        #pragma unroll
        for (int i = 0; i < 4; ++i)
            aF[i] = *(const bf16x8*)&ldsA[(wr + i * 16 + ln) * LDS_S + q * 8];
        #pragma unroll
        for (int j = 0; j < 4; ++j)
            bF[j] = *(const bf16x8*)&ldsB[(wc + j * 16 + ln) * LDS_S + q * 8];
        #pragma unroll
        for (int i = 0; i < 4; ++i)
            #pragma unroll
            for (int j = 0; j < 4; ++j)
                acc[i][j] = __builtin_amdgcn_mfma_f32_16x16x32_bf16(aF[i], bF[j], acc[i][j], 0, 0, 0);

        __syncthreads();
    }

    #pragma unroll
    for (int j = 0; j < 4; ++j) {
        const int c = col0 + wc + j * 16 + ln;
        const float bv = bias[m * 512 + c];
        #pragma unroll
        for (int i = 0; i < 4; ++i) {
            const int r = row0 + wr + i * 16 + q * 4;
            float* op = Out + (size_t)r * 32768 + m * 512 + c;
            f32x4 v = acc[i][j];
            #pragma unroll
            for (int t = 0; t < 4; ++t) {
                float val = v[t] + bv;
                op[(size_t)t * 32768] = val > 0.0f ? val : 0.0f;
            }
        }
    }
}

extern "C" void kernel_launch(void* const* d_in, const int* in_sizes, int n_in,
                              void* d_out, int out_size, void* d_ws, size_t ws_size,
                              hipStream_t stream) {
    const float* x    = (const float*)d_in[0];   // [2048, 64, 512]
    const float* W    = (const float*)d_in[1];   // [64, 512, 512]
    const float* bias = (const float*)d_in[2];   // [64, 512]
    float* out = (float*)d_out;                  // [2048, 64*512]

    const size_t wt_bytes = (size_t)64 * 512 * 512 * sizeof(short);  // 33.55 MB
    if (ws_size >= wt_bytes) {
        short* Wt = (short*)d_ws;
        hipLaunchKernelGGL(wt_prep_kernel, dim3(8, 8, 64), dim3(256), 0, stream, W, Wt);
        hipLaunchKernelGGL(pdense_main3, dim3(4096), dim3(256), 0, stream, x, Wt, bias, out);
    } else {
        hipLaunchKernelGGL(pdense_fallback, dim3(64, 64), dim3(256), 0, stream, x, W, bias, out);
    }
}